// Round 1
// 413.964 us; speedup vs baseline: 1.0006x; 1.0006x over previous
//
#include <hip/hip_runtime.h>

typedef unsigned int u32;
typedef unsigned long long u64;

#define MAXB 8

// Monotone map: fp32 bits -> u32 key, ascending in float value (no NaNs in data).
__device__ __forceinline__ u32 mono(float f) {
    u32 u = __float_as_uint(f);
    return (u & 0x80000000u) ? ~u : (u | 0x80000000u);
}

// ---------------- single-kernel per-batch 3-level radix select ----------------
// One block per batch (batch_ids sorted => contiguous range). 1024 threads.
// Key split: [31:21] (2048 bins) -> [20:10] (2048 bins) -> [9:0] (1024 bins).
// Histograms live in LDS (8 KB), selects are wave-level suffix scans.

struct SelShared {
    u32 h[2048];
    u32 wtot[16];
    u32 wsuf[17];
    u32 selbin;
    u32 selrem;
    int deficient;
    int cnt_s;
};

// Suffix-select over NB bins (1024 or 2048) with 1024 threads.
// Finds largest bin with suffix_count >= target; selrem = target - suffix(bin+1).
__device__ void suffix_select(SelShared* sh, int NB, u32 target) {
    const int t = threadIdx.x;
    const int lane = t & 63;
    const int w = t >> 6;
    const int bpt = NB >> 10;               // bins per thread: 1 or 2
    const u32 b0 = (u32)t * (u32)bpt;
    u32 tot = sh->h[b0];
    if (bpt == 2) tot += sh->h[b0 + 1];
    // in-wave inclusive suffix sum (descending from high lanes)
    u32 x = tot;
#pragma unroll
    for (int d = 1; d < 64; d <<= 1) {
        u32 y = __shfl_down(x, d);
        if (lane + d < 64) x += y;
    }
    if (lane == 0) sh->wtot[w] = x;         // wave total
    __syncthreads();
    if (t == 0) {
        u32 run = 0;
        for (int i = 15; i >= 0; --i) { sh->wsuf[i] = run + sh->wtot[i]; run += sh->wtot[i]; }
        sh->wsuf[16] = 0;
        sh->deficient = (sh->wsuf[0] < target) ? 1 : 0;
    }
    __syncthreads();
    if (sh->deficient) return;
    u32 s_t = x + sh->wsuf[w + 1];          // suffix including this thread's bins
    u32 s_next = s_t - tot;                 // suffix excluding them
    if (s_t >= target && s_next < target) { // exactly one thread
        u32 run = s_next;
        for (int q = bpt - 1; q >= 0; --q) {
            u32 c = sh->h[b0 + q];
            if (run + c >= target) { sh->selbin = b0 + (u32)q; sh->selrem = target - run; break; }
            run += c;
        }
    }
    __syncthreads();
}

// lower_bound over sorted bids: first index with bids[idx] >= v.
// Two-level: stride-1024 sampling, then ballot-count inside one 1024 window.
__device__ int lb_sorted(const int* __restrict__ bids, int N, int v, SelShared* sh) {
    const int t = threadIdx.x;
    if (t == 0) sh->cnt_s = -1;
    __syncthreads();
    int nS = (N + 1023) >> 10;
    if (t < nS && bids[t << 10] < v) atomicMax(&sh->cnt_s, t);
    __syncthreads();
    int c = sh->cnt_s;
    int base = (c < 0) ? 0 : (c << 10);
    __syncthreads();
    if (t == 0) sh->cnt_s = 0;
    __syncthreads();
    int i = base + t;
    int pred = (i < N && bids[i] < v) ? 1 : 0;
    u64 m = __ballot(pred);
    if ((t & 63) == 0) atomicAdd(&sh->cnt_s, (int)__popcll(m));
    __syncthreads();
    int cnt = sh->cnt_s;
    __syncthreads();
    return base + cnt;
}

__global__ __launch_bounds__(1024) void k_select(
    const float* __restrict__ scores, const int* __restrict__ bids,
    const int* __restrict__ kptr, u32* __restrict__ thresh, int N) {
    __shared__ SelShared sh;
    const int t = threadIdx.x;
    const int b = blockIdx.x;
    const u32 target = (u32)kptr[0];

    int start = lb_sorted(bids, N, b, &sh);
    int end   = lb_sorted(bids, N, b + 1, &sh);

    // ---- Level 1: bins = key >> 21 ----
    for (int q = t; q < 2048; q += 1024) sh.h[q] = 0;
    __syncthreads();
    for (int i = start + t; i < end; i += 1024)
        atomicAdd(&sh.h[mono(scores[i]) >> 21], 1u);
    __syncthreads();
    suffix_select(&sh, 2048, target);
    if (sh.deficient) { if (t == 0) thresh[b] = 0u; return; }  // all pass
    u32 p1 = sh.selbin, r1 = sh.selrem;
    __syncthreads();

    // ---- Level 2: keys with hi11 == p1; bins = (key >> 10) & 0x7FF ----
    for (int q = t; q < 2048; q += 1024) sh.h[q] = 0;
    __syncthreads();
    for (int i = start + t; i < end; i += 1024) {
        u32 key = mono(scores[i]);
        if ((key >> 21) == p1) atomicAdd(&sh.h[(key >> 10) & 0x7FFu], 1u);
    }
    __syncthreads();
    suffix_select(&sh, 2048, r1);
    u32 p2 = sh.selbin, r2 = sh.selrem;
    __syncthreads();

    // ---- Level 3: keys with hi22 == (p1<<11|p2); bins = key & 0x3FF ----
    for (int q = t; q < 1024; q += 1024) sh.h[q] = 0;
    __syncthreads();
    const u32 pref = (p1 << 11) | p2;
    for (int i = start + t; i < end; i += 1024) {
        u32 key = mono(scores[i]);
        if ((key >> 10) == pref) atomicAdd(&sh.h[key & 0x3FFu], 1u);
    }
    __syncthreads();
    suffix_select(&sh, 1024, r2);
    if (t == 0) thresh[b] = (pref << 10) | sh.selbin;
}

// ---------------- fused mask + per-point matmul ----------------
// Block owns 512 points. Phase 1: alive test, default rows for dead, LDS-compact
// alive ids. Phase 2: TWO lanes per alive row (128 channels each) -> ~100% lane
// utilization; one shfl_xor(1) reduce per output; coalesced 48 B stores per lane.
__global__ __launch_bounds__(256) void k_fused(
    const float* __restrict__ feats, const float* __restrict__ scores,
    const int* __restrict__ bids, const u32* __restrict__ thresh,
    const float* __restrict__ wreg, const float* __restrict__ wcls,
    const float* __restrict__ bcls, const float* __restrict__ scalep,
    float* __restrict__ out, int N) {

    __shared__ float W[256 * 24];     // weights, scale folded into first 6 cols
    __shared__ u32 alive_idx[512];
    __shared__ u32 nAlive;
    __shared__ float defrow[24];      // pruned-row constants: {1.0 x6, b_cls}

    float scl = scalep[0];
    for (int idx = threadIdx.x; idx < 256 * 24; idx += 256) {
        int c = idx / 24, j = idx - c * 24;
        W[idx] = (j < 6) ? scl * wreg[c * 6 + j] : wcls[c * 18 + (j - 6)];
    }
    if (threadIdx.x == 0) nAlive = 0;
    if (threadIdx.x < 24) defrow[threadIdx.x] = (threadIdx.x < 6) ? 1.0f : bcls[threadIdx.x - 6];
    __syncthreads();

    const int base = blockIdx.x * 512;
#pragma unroll
    for (int q = 0; q < 2; ++q) {
        int i = base + threadIdx.x + q * 256;
        if (i < N) {
            bool alive = mono(scores[i]) >= thresh[bids[i]];
            if (alive) {
                u32 p = atomicAdd(&nAlive, 1u);
                alive_idx[p] = (u32)i;
            } else {
                float4* op = (float4*)(out + (size_t)i * 24);
                const float4* s4 = (const float4*)defrow;
#pragma unroll
                for (int w = 0; w < 6; ++w) op[w] = s4[w];
            }
        }
    }
    __syncthreads();
    const u32 cnt = nAlive;

    const int h   = threadIdx.x & 1;   // which 128-channel half
    const int pid = threadIdx.x >> 1;  // pair id: 128 pairs per block
    for (u32 r = pid; r < cnt; r += 128) {
        u32 i = alive_idx[r];
        const float* row = feats + (size_t)i * 256 + h * 128;
        const float* Wh  = &W[h * 128 * 24];
        float acc[24];
#pragma unroll
        for (int j = 0; j < 24; ++j) acc[j] = 0.f;
        for (int c0 = 0; c0 < 128; c0 += 8) {
            float4 a = *(const float4*)(row + c0);
            float4 bq = *(const float4*)(row + c0 + 4);
            float f[8] = {a.x, a.y, a.z, a.w, bq.x, bq.y, bq.z, bq.w};
#pragma unroll
            for (int tt = 0; tt < 8; ++tt) {
                const float* wr = &Wh[(c0 + tt) * 24];
#pragma unroll
                for (int j = 0; j < 24; j += 4) {
                    float4 w4 = *(const float4*)(wr + j);
                    acc[j + 0] += f[tt] * w4.x;
                    acc[j + 1] += f[tt] * w4.y;
                    acc[j + 2] += f[tt] * w4.z;
                    acc[j + 3] += f[tt] * w4.w;
                }
            }
        }
        // combine the two halves (2-way butterfly within the pair)
#pragma unroll
        for (int j = 0; j < 24; ++j) acc[j] += __shfl_xor(acc[j], 1);
        // lane h writes outputs [h*12, h*12+12)
        __align__(16) float o[12];
        if (h == 0) {
#pragma unroll
            for (int j = 0; j < 6; ++j) o[j] = __expf(acc[j]);
#pragma unroll
            for (int j = 6; j < 12; ++j) o[j] = acc[j] + defrow[j];
        } else {
#pragma unroll
            for (int j = 0; j < 12; ++j) o[j] = acc[12 + j] + defrow[12 + j];
        }
        float4* op = (float4*)(out + (size_t)i * 24 + h * 12);
        const float4* s4 = (const float4*)o;
#pragma unroll
        for (int w = 0; w < 3; ++w) op[w] = s4[w];
    }
}

extern "C" void kernel_launch(void* const* d_in, const int* in_sizes, int n_in,
                              void* d_out, int out_size, void* d_ws, size_t ws_size,
                              hipStream_t stream) {
    const float* feats  = (const float*)d_in[0];
    const float* scores = (const float*)d_in[1];
    const float* wreg   = (const float*)d_in[2];
    const float* wcls   = (const float*)d_in[3];
    const float* bcls   = (const float*)d_in[4];
    const float* scalep = (const float*)d_in[5];
    const int*   bids   = (const int*)d_in[6];
    const int*   kptr   = (const int*)d_in[8];  // pts_threshold
    float* out = (float*)d_out;
    const int N = in_sizes[6];

    // ws: thresh[8] only — no global histograms, no memset needed.
    u32* thresh = (u32*)d_ws;

    k_select<<<MAXB, 1024, 0, stream>>>(scores, bids, kptr, thresh, N);
    k_fused<<<(N + 511) / 512, 256, 0, stream>>>(feats, scores, bids, thresh,
                                                 wreg, wcls, bcls, scalep, out, N);
}